// Round 1
// baseline (544.339 us; speedup 1.0000x reference)
//
#include <hip/hip_runtime.h>
#include <hip/hip_bf16.h>

// out[b,s,o] = sum_i x[b,s,i] * w[o,i]  -- NT GEMM M=8192, N=4096, K=4096
// w dequantized from 4-bit groups (256 vals/group, 16 groups per output row).

#define M_DIM 8192
#define N_DIM 4096
#define K_DIM 4096

typedef __bf16 bf16x8 __attribute__((ext_vector_type(8)));
typedef float f32x4 __attribute__((ext_vector_type(4)));

__device__ __forceinline__ unsigned short f2bf_rne(float f) {
    unsigned int u = __builtin_bit_cast(unsigned int, f);
    u += 0x7FFFu + ((u >> 16) & 1u);
    return (unsigned short)(u >> 16);
}

// ---- prepass 1: x fp32 -> bf16 (ushort) -------------------------------------
__global__ void convert_x_kernel(const float* __restrict__ x,
                                 ushort* __restrict__ a, int n4) {
    int i = blockIdx.x * blockDim.x + threadIdx.x;
    if (i >= n4) return;
    float4 v = ((const float4*)x)[i];
    ushort4 o;
    o.x = f2bf_rne(v.x);
    o.y = f2bf_rne(v.y);
    o.z = f2bf_rne(v.z);
    o.w = f2bf_rne(v.w);
    ((ushort4*)a)[i] = o;
}

// ---- prepass 2: dequant 4-bit -> bf16 W[N][K] row-major ---------------------
// flat w index f = o*4096+i; group g = f/256; packed[g*128+j] -> (f=2j, f=2j+1)
__global__ void dequant_kernel(const int* __restrict__ packed,
                               const float* __restrict__ params,
                               ushort* __restrict__ w, int n) {
    int j = blockIdx.x * blockDim.x + threadIdx.x;
    if (j >= n) return;
    int g = j >> 7;                       // 128 packed ints per group
    int v = packed[j];
    float scale = params[2 * g];
    float zero  = params[2 * g + 1];
    float lo = (float)(v & 15) * scale + zero;
    float hi = (float)((v >> 4) & 15) * scale + zero;
    unsigned int o = (unsigned int)f2bf_rne(lo) | ((unsigned int)f2bf_rne(hi) << 16);
    ((unsigned int*)w)[j] = o;            // two consecutive bf16
}

// ---- main GEMM: m97 structure -----------------------------------------------
// C[M][N] = A[M][K] * B[N][K]^T, bf16 in, fp32 out.
// 128x128 tile, BK=32, 256 threads (4 waves), each wave a 64x64 subtile
// as 4x4 grid of 16x16x32 MFMAs. global_load_lds width=16 staging.
__global__ __launch_bounds__(256, 2) void gemm_bt(const ushort* __restrict__ A,
                                                  const ushort* __restrict__ B,
                                                  float* __restrict__ C) {
    __shared__ __bf16 lds_a[128 * 32];   // 8 KB, row-major 128 rows x 32 (k)
    __shared__ __bf16 lds_b[128 * 32];   // 8 KB

    const int tid  = threadIdx.x;
    const int w    = tid >> 6;           // wave 0..3
    const int lane = tid & 63;
    const int quad = lane >> 4;          // 0..3
    const int l16  = lane & 15;

    const int m0 = blockIdx.y * 128;
    const int n0 = blockIdx.x * 128;
    const int wm = (w >> 1) * 64;        // wave row offset in tile
    const int wn = (w & 1) * 64;         // wave col offset in tile

    f32x4 acc[4][4] = {};

    // staging: 2 rounds of 256 threads x 16B per tile (8 KB each)
    // chunk c (16B) -> tile row c>>2, k-offset (c&3)*8 elems
    const int row0 = tid >> 2,        col0 = (tid & 3) * 8;
    const int row1 = (256 + tid) >> 2, col1 = (tid & 3) * 8;

    const ushort* aptr0 = A + (size_t)(m0 + row0) * K_DIM + col0;
    const ushort* aptr1 = A + (size_t)(m0 + row1) * K_DIM + col1;
    const ushort* bptr0 = B + (size_t)(n0 + row0) * K_DIM + col0;
    const ushort* bptr1 = B + (size_t)(n0 + row1) * K_DIM + col1;

    // wave-uniform LDS dests; HW adds lane*16B
    __bf16* lda0 = &lds_a[w * 512];
    __bf16* lda1 = &lds_a[2048 + w * 512];
    __bf16* ldb0 = &lds_b[w * 512];
    __bf16* ldb1 = &lds_b[2048 + w * 512];

    for (int k0 = 0; k0 < K_DIM; k0 += 32) {
        __builtin_amdgcn_global_load_lds(
            (const __attribute__((address_space(1))) void*)(aptr0 + k0),
            (__attribute__((address_space(3))) void*)lda0, 16, 0, 0);
        __builtin_amdgcn_global_load_lds(
            (const __attribute__((address_space(1))) void*)(aptr1 + k0),
            (__attribute__((address_space(3))) void*)lda1, 16, 0, 0);
        __builtin_amdgcn_global_load_lds(
            (const __attribute__((address_space(1))) void*)(bptr0 + k0),
            (__attribute__((address_space(3))) void*)ldb0, 16, 0, 0);
        __builtin_amdgcn_global_load_lds(
            (const __attribute__((address_space(1))) void*)(bptr1 + k0),
            (__attribute__((address_space(3))) void*)ldb1, 16, 0, 0);

        __syncthreads();   // staging complete (compiler drains vmcnt)

        bf16x8 af[4], bfv[4];
#pragma unroll
        for (int i = 0; i < 4; ++i) {
            af[i]  = *(const bf16x8*)&lds_a[(wm + i * 16 + l16) * 32 + quad * 8];
            bfv[i] = *(const bf16x8*)&lds_b[(wn + i * 16 + l16) * 32 + quad * 8];
        }
#pragma unroll
        for (int i = 0; i < 4; ++i)
#pragma unroll
            for (int j = 0; j < 4; ++j)
                acc[i][j] = __builtin_amdgcn_mfma_f32_16x16x32_bf16(
                    af[i], bfv[j], acc[i][j], 0, 0, 0);

        __syncthreads();   // reads done before next overwrite
    }

    // epilogue: C/D layout col=lane&15, row=quad*4+reg (m89/m91-verified)
    const int crow = m0 + wm + quad * 4;
    const int ccol = n0 + wn + l16;
#pragma unroll
    for (int i = 0; i < 4; ++i)
#pragma unroll
        for (int j = 0; j < 4; ++j)
#pragma unroll
            for (int r = 0; r < 4; ++r)
                C[(size_t)(crow + i * 16 + r) * N_DIM + ccol + j * 16] = acc[i][j][r];
}

// ---- emergency fallback (only if ws too small) ------------------------------
__global__ void naive_kernel(const float* __restrict__ x, const int* __restrict__ packed,
                             const float* __restrict__ params, float* __restrict__ out) {
    int idx = blockIdx.x * blockDim.x + threadIdx.x;
    if (idx >= M_DIM * N_DIM) return;
    int m = idx / N_DIM, o = idx % N_DIM;
    const float* xr = x + (size_t)m * K_DIM;
    float sum = 0.f;
    for (int gi = 0; gi < K_DIM / 256; ++gi) {
        int g = o * (K_DIM / 256) + gi;
        float s = params[2 * g], z = params[2 * g + 1];
        const int* p = packed + (size_t)g * 128;
        const float* xx = xr + gi * 256;
        for (int j = 0; j < 128; ++j) {
            int v = p[j];
            sum += xx[2 * j]     * ((float)(v & 15) * s + z);
            sum += xx[2 * j + 1] * ((float)((v >> 4) & 15) * s + z);
        }
    }
    out[idx] = sum;
}

extern "C" void kernel_launch(void* const* d_in, const int* in_sizes, int n_in,
                              void* d_out, int out_size, void* d_ws, size_t ws_size,
                              hipStream_t stream) {
    const float* x      = (const float*)d_in[0];
    const int*   packed = (const int*)d_in[1];
    const float* params = (const float*)d_in[2];
    float* out = (float*)d_out;

    const size_t a_bytes = (size_t)M_DIM * K_DIM * 2;   // 67.1 MB bf16 x
    const size_t w_bytes = (size_t)N_DIM * K_DIM * 2;   // 33.6 MB bf16 W

    if (ws_size >= a_bytes + w_bytes) {
        ushort* Abf = (ushort*)d_ws;
        ushort* Wbf = (ushort*)((char*)d_ws + a_bytes);

        int n4 = M_DIM * K_DIM / 4;     // 8,388,608 float4 groups
        convert_x_kernel<<<(n4 + 255) / 256, 256, 0, stream>>>(x, Abf, n4);

        int np = N_DIM * K_DIM / 2;     // 8,388,608 packed int32
        dequant_kernel<<<(np + 255) / 256, 256, 0, stream>>>(packed, params, Wbf, np);

        dim3 grid(N_DIM / 128, M_DIM / 128);   // 32 x 64 = 2048 blocks
        gemm_bt<<<grid, 256, 0, stream>>>(Abf, Wbf, out);
    } else {
        int n = M_DIM * N_DIM;
        naive_kernel<<<(n + 255) / 256, 256, 0, stream>>>(x, packed, params, out);
    }
}

// Round 2
// 533.376 us; speedup vs baseline: 1.0206x; 1.0206x over previous
//
#include <hip/hip_runtime.h>
#include <hip/hip_bf16.h>

// out[b,s,o] = sum_i x[b,s,i] * w[o,i]  -- NT GEMM M=8192, N=4096, K=4096
// w dequantized from 4-bit groups (256 vals/group, 16 groups per output row).

#define M_DIM 8192
#define N_DIM 4096
#define K_DIM 4096

typedef __bf16 bf16x8 __attribute__((ext_vector_type(8)));
typedef float f32x4 __attribute__((ext_vector_type(4)));
typedef unsigned short us8 __attribute__((ext_vector_type(8)));

__device__ __forceinline__ unsigned short f2bf_rne(float f) {
    unsigned int u = __builtin_bit_cast(unsigned int, f);
    u += 0x7FFFu + ((u >> 16) & 1u);
    return (unsigned short)(u >> 16);
}

// ---- fused prepass ----------------------------------------------------------
// blocks [0,16384): x fp32 -> bf16, 8 floats/thread (16 B store)
// blocks [16384,24576): dequant 4-bit -> bf16 W[N][K], 4 packed ints/thread
__global__ void prep_kernel(const float* __restrict__ x,
                            const int* __restrict__ packed,
                            const float* __restrict__ params,
                            ushort* __restrict__ a,
                            ushort* __restrict__ w) {
    int b = blockIdx.x;
    if (b < 16384) {
        int j = b * 256 + threadIdx.x;        // ushort8 index
        float4 v0 = ((const float4*)x)[2 * j];
        float4 v1 = ((const float4*)x)[2 * j + 1];
        us8 o;
        o[0] = f2bf_rne(v0.x); o[1] = f2bf_rne(v0.y);
        o[2] = f2bf_rne(v0.z); o[3] = f2bf_rne(v0.w);
        o[4] = f2bf_rne(v1.x); o[5] = f2bf_rne(v1.y);
        o[6] = f2bf_rne(v1.z); o[7] = f2bf_rne(v1.w);
        ((us8*)a)[j] = o;
    } else {
        int j = (b - 16384) * 256 + threadIdx.x;   // int4 index
        int4 v = ((const int4*)packed)[j];
        int g = j >> 5;                            // (4j)>>7: 4 ints same group
        float s = params[2 * g], z = params[2 * g + 1];
        unsigned int o0, o1, o2, o3;
        o0 = (unsigned int)f2bf_rne((float)(v.x & 15) * s + z)
           | ((unsigned int)f2bf_rne((float)((v.x >> 4) & 15) * s + z) << 16);
        o1 = (unsigned int)f2bf_rne((float)(v.y & 15) * s + z)
           | ((unsigned int)f2bf_rne((float)((v.y >> 4) & 15) * s + z) << 16);
        o2 = (unsigned int)f2bf_rne((float)(v.z & 15) * s + z)
           | ((unsigned int)f2bf_rne((float)((v.z >> 4) & 15) * s + z) << 16);
        o3 = (unsigned int)f2bf_rne((float)(v.w & 15) * s + z)
           | ((unsigned int)f2bf_rne((float)((v.w >> 4) & 15) * s + z) << 16);
        ((uint4*)w)[j] = make_uint4(o0, o1, o2, o3);
    }
}

// ---- main GEMM: m97 structure + XOR chunk swizzle ---------------------------
// C[M][N] = A[M][K] * B[N][K]^T, bf16 in, fp32 out.
// 128x128 tile, BK=32, 256 threads (4 waves), each wave a 64x64 subtile
// as 4x4 grid of 16x16x32 MFMAs. global_load_lds width=16 staging.
// Bank-conflict fix: LDS slot (row r, chunk c) holds global chunk c^((r>>1)&3)
// -> fragment reads spread uniformly 2-way over banks (2-way is free, m136).
__global__ __launch_bounds__(256, 4) void gemm_bt(const ushort* __restrict__ A,
                                                  const ushort* __restrict__ B,
                                                  float* __restrict__ C) {
    __shared__ __bf16 lds_a[128 * 32];   // 8 KB, 128 rows x 32 k-elems
    __shared__ __bf16 lds_b[128 * 32];   // 8 KB

    const int tid  = threadIdx.x;
    const int w    = tid >> 6;           // wave 0..3
    const int lane = tid & 63;
    const int quad = lane >> 4;          // 0..3
    const int l16  = lane & 15;

    const int m0 = blockIdx.y * 128;
    const int n0 = blockIdx.x * 128;
    const int wm = (w >> 1) * 64;        // wave row offset in tile
    const int wn = (w & 1) * 64;         // wave col offset in tile

    f32x4 acc[4][4] = {};

    // staging: thread t fills LDS slot t (round0) / 256+t (round1); slot s =
    // (row s>>2, chunk s&3). Source chunk is XOR-swizzled by (row>>1)&3; the
    // swizzle is identical for both rounds (row1 = row0 + 64, 64 ≡ 0 mod 8).
    const int row0 = tid >> 2;
    const int row1 = 64 + row0;
    const int swz  = (tid >> 3) & 3;               // (row>>1)&3
    const int col  = ((tid & 3) ^ swz) * 8;        // swizzled k-offset (elems)

    const ushort* aptr0 = A + (size_t)(m0 + row0) * K_DIM + col;
    const ushort* aptr1 = A + (size_t)(m0 + row1) * K_DIM + col;
    const ushort* bptr0 = B + (size_t)(n0 + row0) * K_DIM + col;
    const ushort* bptr1 = B + (size_t)(n0 + row1) * K_DIM + col;

    // wave-uniform LDS dests; HW adds lane*16B
    __bf16* lda0 = &lds_a[w * 512];
    __bf16* lda1 = &lds_a[2048 + w * 512];
    __bf16* ldb0 = &lds_b[w * 512];
    __bf16* ldb1 = &lds_b[2048 + w * 512];

    // fragment-read swizzle: row = wm+i*16+l16 -> (row>>1)&3 == (l16>>1)&3
    const int rq = (quad ^ ((l16 >> 1) & 3)) * 8;

    for (int k0 = 0; k0 < K_DIM; k0 += 32) {
        __builtin_amdgcn_global_load_lds(
            (const __attribute__((address_space(1))) void*)(aptr0 + k0),
            (__attribute__((address_space(3))) void*)lda0, 16, 0, 0);
        __builtin_amdgcn_global_load_lds(
            (const __attribute__((address_space(1))) void*)(aptr1 + k0),
            (__attribute__((address_space(3))) void*)lda1, 16, 0, 0);
        __builtin_amdgcn_global_load_lds(
            (const __attribute__((address_space(1))) void*)(bptr0 + k0),
            (__attribute__((address_space(3))) void*)ldb0, 16, 0, 0);
        __builtin_amdgcn_global_load_lds(
            (const __attribute__((address_space(1))) void*)(bptr1 + k0),
            (__attribute__((address_space(3))) void*)ldb1, 16, 0, 0);

        __syncthreads();   // staging complete (compiler drains vmcnt)

        bf16x8 af[4], bfv[4];
#pragma unroll
        for (int i = 0; i < 4; ++i) {
            af[i]  = *(const bf16x8*)&lds_a[(wm + i * 16 + l16) * 32 + rq];
            bfv[i] = *(const bf16x8*)&lds_b[(wn + i * 16 + l16) * 32 + rq];
        }
#pragma unroll
        for (int i = 0; i < 4; ++i)
#pragma unroll
            for (int j = 0; j < 4; ++j)
                acc[i][j] = __builtin_amdgcn_mfma_f32_16x16x32_bf16(
                    af[i], bfv[j], acc[i][j], 0, 0, 0);

        __syncthreads();   // reads done before next overwrite
    }

    // epilogue: C/D layout col=lane&15, row=quad*4+reg (m89/m91-verified)
    const int crow = m0 + wm + quad * 4;
    const int ccol = n0 + wn + l16;
#pragma unroll
    for (int i = 0; i < 4; ++i)
#pragma unroll
        for (int j = 0; j < 4; ++j)
#pragma unroll
            for (int r = 0; r < 4; ++r)
                C[(size_t)(crow + i * 16 + r) * N_DIM + ccol + j * 16] = acc[i][j][r];
}

// ---- emergency fallback (only if ws too small) ------------------------------
__global__ void naive_kernel(const float* __restrict__ x, const int* __restrict__ packed,
                             const float* __restrict__ params, float* __restrict__ out) {
    int idx = blockIdx.x * blockDim.x + threadIdx.x;
    if (idx >= M_DIM * N_DIM) return;
    int m = idx / N_DIM, o = idx % N_DIM;
    const float* xr = x + (size_t)m * K_DIM;
    float sum = 0.f;
    for (int gi = 0; gi < K_DIM / 256; ++gi) {
        int g = o * (K_DIM / 256) + gi;
        float s = params[2 * g], z = params[2 * g + 1];
        const int* p = packed + (size_t)g * 128;
        const float* xx = xr + gi * 256;
        for (int j = 0; j < 128; ++j) {
            int v = p[j];
            sum += xx[2 * j]     * ((float)(v & 15) * s + z);
            sum += xx[2 * j + 1] * ((float)((v >> 4) & 15) * s + z);
        }
    }
    out[idx] = sum;
}

extern "C" void kernel_launch(void* const* d_in, const int* in_sizes, int n_in,
                              void* d_out, int out_size, void* d_ws, size_t ws_size,
                              hipStream_t stream) {
    const float* x      = (const float*)d_in[0];
    const int*   packed = (const int*)d_in[1];
    const float* params = (const float*)d_in[2];
    float* out = (float*)d_out;

    const size_t a_bytes = (size_t)M_DIM * K_DIM * 2;   // 67.1 MB bf16 x
    const size_t w_bytes = (size_t)N_DIM * K_DIM * 2;   // 33.6 MB bf16 W

    if (ws_size >= a_bytes + w_bytes) {
        ushort* Abf = (ushort*)d_ws;
        ushort* Wbf = (ushort*)((char*)d_ws + a_bytes);

        // 16384 convert blocks + 8192 dequant blocks
        prep_kernel<<<24576, 256, 0, stream>>>(x, packed, params, Abf, Wbf);

        dim3 grid(N_DIM / 128, M_DIM / 128);   // 32 x 64 = 2048 blocks
        gemm_bt<<<grid, 256, 0, stream>>>(Abf, Wbf, out);
    } else {
        int n = M_DIM * N_DIM;
        naive_kernel<<<(n + 255) / 256, 256, 0, stream>>>(x, packed, params, out);
    }
}

// Round 3
// 474.540 us; speedup vs baseline: 1.1471x; 1.1240x over previous
//
#include <hip/hip_runtime.h>
#include <hip/hip_bf16.h>

// out[b,s,o] = sum_i x[b,s,i] * w[o,i]  -- NT GEMM M=8192, N=4096, K=4096
// w dequantized from 4-bit groups (256 vals/group, 16 groups per output row).

#define M_DIM 8192
#define N_DIM 4096
#define K_DIM 4096

typedef __bf16 bf16x8 __attribute__((ext_vector_type(8)));
typedef float f32x4 __attribute__((ext_vector_type(4)));
typedef unsigned short us8 __attribute__((ext_vector_type(8)));

__device__ __forceinline__ unsigned short f2bf_rne(float f) {
    unsigned int u = __builtin_bit_cast(unsigned int, f);
    u += 0x7FFFu + ((u >> 16) & 1u);
    return (unsigned short)(u >> 16);
}

// ---- fused prepass ----------------------------------------------------------
// blocks [0,16384): x fp32 -> bf16, 8 floats/thread (16 B store)
// blocks [16384,24576): dequant 4-bit -> bf16 W[N][K], 4 packed ints/thread
__global__ void prep_kernel(const float* __restrict__ x,
                            const int* __restrict__ packed,
                            const float* __restrict__ params,
                            ushort* __restrict__ a,
                            ushort* __restrict__ w) {
    int b = blockIdx.x;
    if (b < 16384) {
        int j = b * 256 + threadIdx.x;        // ushort8 index
        float4 v0 = ((const float4*)x)[2 * j];
        float4 v1 = ((const float4*)x)[2 * j + 1];
        us8 o;
        o[0] = f2bf_rne(v0.x); o[1] = f2bf_rne(v0.y);
        o[2] = f2bf_rne(v0.z); o[3] = f2bf_rne(v0.w);
        o[4] = f2bf_rne(v1.x); o[5] = f2bf_rne(v1.y);
        o[6] = f2bf_rne(v1.z); o[7] = f2bf_rne(v1.w);
        ((us8*)a)[j] = o;
    } else {
        int j = (b - 16384) * 256 + threadIdx.x;   // int4 index
        int4 v = ((const int4*)packed)[j];
        int g = j >> 5;                            // (4j)>>7: 4 ints same group
        float s = params[2 * g], z = params[2 * g + 1];
        unsigned int o0, o1, o2, o3;
        o0 = (unsigned int)f2bf_rne((float)(v.x & 15) * s + z)
           | ((unsigned int)f2bf_rne((float)((v.x >> 4) & 15) * s + z) << 16);
        o1 = (unsigned int)f2bf_rne((float)(v.y & 15) * s + z)
           | ((unsigned int)f2bf_rne((float)((v.y >> 4) & 15) * s + z) << 16);
        o2 = (unsigned int)f2bf_rne((float)(v.z & 15) * s + z)
           | ((unsigned int)f2bf_rne((float)((v.z >> 4) & 15) * s + z) << 16);
        o3 = (unsigned int)f2bf_rne((float)(v.w & 15) * s + z)
           | ((unsigned int)f2bf_rne((float)((v.w >> 4) & 15) * s + z) << 16);
        ((uint4*)w)[j] = make_uint4(o0, o1, o2, o3);
    }
}

// ---- main GEMM: m97 structure, BK=64 ----------------------------------------
// C[M][N] = A[M][K] * B[N][K]^T, bf16 in, fp32 out.
// 128x128 tile, BK=64 (halves barrier-drain rounds vs BK=32; LDS 32 KB/block
// keeps ~4 blocks/CU, unlike m132's BK=128 64 KB cliff). 256 threads (4
// waves), each wave 64x64 as 4x4 of 16x16x32 MFMAs, 2 k-steps per barrier.
// XOR swizzle: LDS slot (row, chunk c in 0..7) holds global chunk c^(row&7);
// every 8-lane b128 phase group hits 8 distinct bank-groups -> conflict-free.
__global__ __launch_bounds__(256, 4) void gemm_bt(const ushort* __restrict__ A,
                                                  const ushort* __restrict__ B,
                                                  float* __restrict__ C) {
    __shared__ __bf16 lds_a[128 * 64];   // 16 KB, 128 rows x 64 k-elems
    __shared__ __bf16 lds_b[128 * 64];   // 16 KB

    const int tid  = threadIdx.x;
    const int w    = tid >> 6;           // wave 0..3
    const int lane = tid & 63;
    const int quad = lane >> 4;          // 0..3
    const int l16  = lane & 15;

    const int m0 = blockIdx.y * 128;
    const int n0 = blockIdx.x * 128;
    const int wm = (w >> 1) * 64;        // wave row offset in tile
    const int wn = (w & 1) * 64;         // wave col offset in tile

    f32x4 acc[4][4] = {};

    // staging: 4 rounds x 256 threads x 16 B per tile. Round rd, thread t ->
    // slot s = rd*256+t: row = rd*32 + (t>>3), lds chunk = t&7.
    // Source chunk = (t&7) ^ ((t>>3)&7)  (row&7 == (t>>3)&7 for all rounds).
    const int srow = tid >> 3;                         // row within round 0
    const int scol = ((tid & 7) ^ (srow & 7)) * 8;     // swizzled k-offset

    const ushort* aptr0 = A + (size_t)(m0 + srow) * K_DIM + scol;
    const ushort* bptr0 = B + (size_t)(n0 + srow) * K_DIM + scol;

    // fragment-read chunk swizzle: row&7 == l16&7 (wm, i*16 are mult of 8)
    const int swz8 = l16 & 7;

    for (int k0 = 0; k0 < K_DIM; k0 += 64) {
#pragma unroll
        for (int rd = 0; rd < 4; ++rd) {
            __builtin_amdgcn_global_load_lds(
                (const __attribute__((address_space(1))) void*)(aptr0 + k0 + rd * 32 * K_DIM),
                (__attribute__((address_space(3))) void*)(lds_a + rd * 2048 + w * 512),
                16, 0, 0);
            __builtin_amdgcn_global_load_lds(
                (const __attribute__((address_space(1))) void*)(bptr0 + k0 + rd * 32 * K_DIM),
                (__attribute__((address_space(3))) void*)(lds_b + rd * 2048 + w * 512),
                16, 0, 0);
        }

        __syncthreads();   // staging complete (compiler drains vmcnt)

#pragma unroll
        for (int ks = 0; ks < 2; ++ks) {
            const int cq = ((ks << 2) + quad);
            bf16x8 af[4], bfv[4];
#pragma unroll
            for (int i = 0; i < 4; ++i) {
                af[i]  = *(const bf16x8*)&lds_a[(wm + i * 16 + l16) * 64 + (cq ^ swz8) * 8];
                bfv[i] = *(const bf16x8*)&lds_b[(wn + i * 16 + l16) * 64 + (cq ^ swz8) * 8];
            }
#pragma unroll
            for (int i = 0; i < 4; ++i)
#pragma unroll
                for (int j = 0; j < 4; ++j)
                    acc[i][j] = __builtin_amdgcn_mfma_f32_16x16x32_bf16(
                        af[i], bfv[j], acc[i][j], 0, 0, 0);
        }

        __syncthreads();   // reads done before next overwrite
    }

    // epilogue: C/D layout col=lane&15, row=quad*4+reg (m89/m91-verified)
    const int crow = m0 + wm + quad * 4;
    const int ccol = n0 + wn + l16;
#pragma unroll
    for (int i = 0; i < 4; ++i)
#pragma unroll
        for (int j = 0; j < 4; ++j)
#pragma unroll
            for (int r = 0; r < 4; ++r)
                C[(size_t)(crow + i * 16 + r) * N_DIM + ccol + j * 16] = acc[i][j][r];
}

// ---- emergency fallback (only if ws too small) ------------------------------
__global__ void naive_kernel(const float* __restrict__ x, const int* __restrict__ packed,
                             const float* __restrict__ params, float* __restrict__ out) {
    int idx = blockIdx.x * blockDim.x + threadIdx.x;
    if (idx >= M_DIM * N_DIM) return;
    int m = idx / N_DIM, o = idx % N_DIM;
    const float* xr = x + (size_t)m * K_DIM;
    float sum = 0.f;
    for (int gi = 0; gi < K_DIM / 256; ++gi) {
        int g = o * (K_DIM / 256) + gi;
        float s = params[2 * g], z = params[2 * g + 1];
        const int* p = packed + (size_t)g * 128;
        const float* xx = xr + gi * 256;
        for (int j = 0; j < 128; ++j) {
            int v = p[j];
            sum += xx[2 * j]     * ((float)(v & 15) * s + z);
            sum += xx[2 * j + 1] * ((float)((v >> 4) & 15) * s + z);
        }
    }
    out[idx] = sum;
}

extern "C" void kernel_launch(void* const* d_in, const int* in_sizes, int n_in,
                              void* d_out, int out_size, void* d_ws, size_t ws_size,
                              hipStream_t stream) {
    const float* x      = (const float*)d_in[0];
    const int*   packed = (const int*)d_in[1];
    const float* params = (const float*)d_in[2];
    float* out = (float*)d_out;

    const size_t a_bytes = (size_t)M_DIM * K_DIM * 2;   // 67.1 MB bf16 x
    const size_t w_bytes = (size_t)N_DIM * K_DIM * 2;   // 33.6 MB bf16 W

    if (ws_size >= a_bytes + w_bytes) {
        ushort* Abf = (ushort*)d_ws;
        ushort* Wbf = (ushort*)((char*)d_ws + a_bytes);

        // 16384 convert blocks + 8192 dequant blocks
        prep_kernel<<<24576, 256, 0, stream>>>(x, packed, params, Abf, Wbf);

        dim3 grid(N_DIM / 128, M_DIM / 128);   // 32 x 64 = 2048 blocks
        gemm_bt<<<grid, 256, 0, stream>>>(Abf, Wbf, out);
    } else {
        int n = M_DIM * N_DIM;
        naive_kernel<<<(n + 255) / 256, 256, 0, stream>>>(x, packed, params, out);
    }
}